// Round 3
// baseline (20698.906 us; speedup 1.0000x reference)
//
#include <hip/hip_runtime.h>
#include <hip/hip_bf16.h>
#include <stdint.h>

typedef _Float16 half8 __attribute__((ext_vector_type(8)));
typedef float f32x4 __attribute__((ext_vector_type(4)));

#define DDIM 256
#define KCODES 4096
#define BM 128
#define BN 256
#define BK 64
#define NTILES (KCODES / BN)   // 16
#define NCHUNK (DDIM / BK)     // 4
#define DELTA 0.05f
#define FLT_BIG 3.4e38f

// ---------------- codebook -> fp16 hi/lo, layout [code][chunk][16B slot] ----------------
// logical slots per 64-dim chunk: 0-3 hi(d0..31), 4-7 lo(d0..31), 8-11 hi(d32..63), 12-15 lo(d32..63)
__global__ void cvt_cb_kernel(const float* __restrict__ cb, half8* __restrict__ cb16) {
    int gid = blockIdx.x * 256 + threadIdx.x;   // 4096*4*16 = 262144
    int slot = gid & 15;
    int chunk = (gid >> 4) & 3;
    int code = gid >> 6;
    int g = slot >> 3, part = (slot >> 2) & 1, quad = slot & 3;
    int d0 = chunk * 64 + g * 32 + quad * 8;
    const float* src = &cb[(size_t)code * DDIM + d0];
    half8 h;
    #pragma unroll
    for (int j = 0; j < 8; ++j) {
        float v = src[j];
        _Float16 hi = (_Float16)v;
        h[j] = part ? (_Float16)(v - (float)hi) : hi;
    }
    cb16[gid] = h;
}

__global__ void enorm_kernel(const float* __restrict__ cb, float* __restrict__ en, int K) {
    int gid = blockIdx.x * blockDim.x + threadIdx.x;
    int code = gid >> 6;
    int lane = threadIdx.x & 63;
    if (code >= K) return;
    const float4 v = *reinterpret_cast<const float4*>(&cb[(size_t)code * DDIM + lane * 4]);
    float s = v.x * v.x + v.y * v.y + v.z * v.z + v.w * v.w;
    #pragma unroll
    for (int off = 32; off > 0; off >>= 1) s += __shfl_xor(s, off, 64);
    if (lane == 0) en[code] = s;
}

// ---------------- main: MFMA distance GEMM + fused argmin + near-tie flag ----------------
__global__ __launch_bounds__(512, 2)
void vq_mfma_kernel(const float* __restrict__ x, const half8* __restrict__ cb16,
                    const float* __restrict__ en, int* __restrict__ bidx_out,
                    unsigned int* __restrict__ flag_out) {
    __shared__ __align__(16) _Float16 Asl[BM * 128];   // 32 KB: 128 rows x 16 slots
    __shared__ __align__(16) _Float16 Bsl[BN * 128];   // 64 KB: 256 rows x 16 slots
    __shared__ float red_d[4][BM];
    __shared__ int   red_i[4][BM];

    const int tid = threadIdx.x;
    const int lane = tid & 63;
    const int w = tid >> 6;
    const int wr = w >> 2, wc = w & 3;       // 2 x 4 waves
    const int l15 = lane & 15, l4 = lane >> 4;
    const int brow = blockIdx.x * BM;

    float best[16];
    int bid[16];
    unsigned int flags = 0;
    #pragma unroll
    for (int i = 0; i < 16; ++i) { best[i] = FLT_BIG; bid[i] = 0; }

    // A staging assignment: thread covers (row = tid>>2, 16 dims at quarter aq)
    const int arow = tid >> 2;
    const int aq = tid & 3;
    const float* axp = &x[(size_t)(brow + arow) * DDIM + aq * 16];
    half8* Ap = (half8*)Asl;
    half8* Bp = (half8*)Bsl;
    const int aswz = arow & 7;
    const int abase = arow * 16;
    const int ah0 = (aq >> 1) * 8 + (aq & 1) * 2;

    for (int ct = 0; ct < NTILES; ++ct) {
        const int c0 = ct * BN;
        f32x4 acc[4][4];
        #pragma unroll
        for (int m = 0; m < 4; ++m)
            #pragma unroll
            for (int n = 0; n < 4; ++n) acc[m][n] = (f32x4){0.f, 0.f, 0.f, 0.f};

        for (int c = 0; c < NCHUNK; ++c) {
            __syncthreads();
            // ---- stage A (fp32 -> hi/lo fp16, swizzled ds_write) ----
            {
                const float4* ax4 = (const float4*)(axp + c * 64);
                float4 f0 = ax4[0], f1 = ax4[1], f2 = ax4[2], f3 = ax4[3];
                float vv[16] = {f0.x, f0.y, f0.z, f0.w, f1.x, f1.y, f1.z, f1.w,
                                f2.x, f2.y, f2.z, f2.w, f3.x, f3.y, f3.z, f3.w};
                half8 hv0, hv1, lv0, lv1;
                #pragma unroll
                for (int j = 0; j < 8; ++j) {
                    _Float16 h = (_Float16)vv[j];
                    hv0[j] = h; lv0[j] = (_Float16)(vv[j] - (float)h);
                }
                #pragma unroll
                for (int j = 0; j < 8; ++j) {
                    _Float16 h = (_Float16)vv[8 + j];
                    hv1[j] = h; lv1[j] = (_Float16)(vv[8 + j] - (float)h);
                }
                Ap[abase + ((ah0    ) ^ aswz)] = hv0;
                Ap[abase + ((ah0 + 1) ^ aswz)] = hv1;
                Ap[abase + ((ah0 + 4) ^ aswz)] = lv0;
                Ap[abase + ((ah0 + 5) ^ aswz)] = lv1;
            }
            // ---- stage B (pre-converted fp16, swizzled ds_write) ----
            #pragma unroll
            for (int i = 0; i < 8; ++i) {
                int S = i * 512 + tid;          // 0..4095 16B-slots
                int r = S >> 4, l = S & 15;
                half8 v = cb16[((size_t)(c0 + r) * NCHUNK + c) * 16 + l];
                Bp[r * 16 + (l ^ (r & 7))] = v;
            }
            __syncthreads();

            // ---- MFMA: 2 groups x 3 terms x 16 fragment-pairs ----
            #pragma unroll
            for (int g = 0; g < 2; ++g) {
                half8 ah[4], al[4], bh[4], bl[4];
                #pragma unroll
                for (int m = 0; m < 4; ++m) {
                    int row = wr * 64 + m * 16 + l15;
                    int sw = row & 7;
                    int sh = g * 8 + l4;
                    ah[m] = Ap[row * 16 + ((sh    ) ^ sw)];
                    al[m] = Ap[row * 16 + ((sh + 4) ^ sw)];
                }
                #pragma unroll
                for (int n = 0; n < 4; ++n) {
                    int col = wc * 64 + n * 16 + l15;
                    int sw = col & 7;
                    int sh = g * 8 + l4;
                    bh[n] = Bp[col * 16 + ((sh    ) ^ sw)];
                    bl[n] = Bp[col * 16 + ((sh + 4) ^ sw)];
                }
                #pragma unroll
                for (int m = 0; m < 4; ++m)
                    #pragma unroll
                    for (int n = 0; n < 4; ++n) {
                        acc[m][n] = __builtin_amdgcn_mfma_f32_16x16x32_f16(ah[m], bh[n], acc[m][n], 0, 0, 0);
                        acc[m][n] = __builtin_amdgcn_mfma_f32_16x16x32_f16(al[m], bh[n], acc[m][n], 0, 0, 0);
                        acc[m][n] = __builtin_amdgcn_mfma_f32_16x16x32_f16(ah[m], bl[n], acc[m][n], 0, 0, 0);
                    }
            }
        }

        // ---- fused argmin epilogue: dist = ||e||^2 - 2*dot ----
        #pragma unroll
        for (int n = 0; n < 4; ++n) {
            int code = c0 + wc * 64 + n * 16 + l15;
            float e = en[code];
            #pragma unroll
            for (int m = 0; m < 4; ++m) {
                #pragma unroll
                for (int r = 0; r < 4; ++r) {
                    float dist = fmaf(-2.f, acc[m][n][r], e);
                    int ri = m * 4 + r;
                    if (dist < best[ri]) {
                        if (best[ri] - dist < DELTA) flags |= (1u << ri);
                        best[ri] = dist; bid[ri] = code;
                    } else if (dist - best[ri] < DELTA) {
                        flags |= (1u << ri);
                    }
                }
            }
        }
    }

    // ---- cross-lane merge (16 lanes sharing same rows) ----
    #pragma unroll
    for (int ri = 0; ri < 16; ++ri) {
        float d = best[ri];
        int ix = bid[ri];
        int fl = (flags >> ri) & 1;
        #pragma unroll
        for (int off = 1; off < 16; off <<= 1) {
            float od = __shfl_xor(d, off, 64);
            int oi = __shfl_xor(ix, off, 64);
            int ofl = __shfl_xor(fl, off, 64);
            fl |= ofl | ((fabsf(od - d) < DELTA) ? 1 : 0);
            if (od < d || (od == d && oi < ix)) { d = od; ix = oi; }
        }
        if (l15 == 0) {
            int row = wr * 64 + (ri >> 2) * 16 + l4 * 4 + (ri & 3);
            red_d[wc][row] = d;
            red_i[wc][row] = (ix & 0xffff) | (fl << 31);
        }
    }
    __syncthreads();

    // ---- cross-wave merge + write ----
    if (tid < BM) {
        float d = red_d[0][tid];
        int p = red_i[0][tid];
        int ix = p & 0xffff;
        unsigned int fl = ((unsigned int)p) >> 31;
        #pragma unroll
        for (int q = 1; q < 4; ++q) {
            float od = red_d[q][tid];
            int op = red_i[q][tid];
            int oi = op & 0xffff;
            fl |= (((unsigned int)op) >> 31) | ((fabsf(od - d) < DELTA) ? 1u : 0u);
            if (od < d || (od == d && oi < ix)) { d = od; ix = oi; }
        }
        bidx_out[brow + tid] = ix;
        flag_out[brow + tid] = fl;
    }
}

// ---------------- exact fp32 rescan for flagged rows ----------------
__global__ void rescan_kernel(const float* __restrict__ x, const float* __restrict__ cb,
                              const float* __restrict__ en, const unsigned int* __restrict__ flags,
                              int* __restrict__ bidx) {
    __shared__ __align__(16) float xrow[DDIM];
    __shared__ float rd[256];
    __shared__ int ri_[256];
    const int tid = threadIdx.x;
    const int base = blockIdx.x * 8;
    for (int rr = 0; rr < 8; ++rr) {
        int row = base + rr;
        if (!flags[row]) continue;      // block-uniform
        __syncthreads();
        if (tid < 64) ((float4*)xrow)[tid] = ((const float4*)&x[(size_t)row * DDIM])[tid];
        __syncthreads();
        float bd = FLT_BIG;
        int bi = 0;
        for (int cc = 0; cc < 16; ++cc) {
            int code = cc * 256 + tid;
            const float4* cp = (const float4*)&cb[(size_t)code * DDIM];
            float dot = 0.f;
            #pragma unroll 8
            for (int j = 0; j < 64; ++j) {
                float4 c4 = cp[j];
                float4 x4 = ((float4*)xrow)[j];
                dot = fmaf(x4.x, c4.x, dot);
                dot = fmaf(x4.y, c4.y, dot);
                dot = fmaf(x4.z, c4.z, dot);
                dot = fmaf(x4.w, c4.w, dot);
            }
            float dist = fmaf(-2.f, dot, en[code]);
            if (dist < bd) { bd = dist; bi = code; }
        }
        rd[tid] = bd; ri_[tid] = bi;
        __syncthreads();
        for (int s = 128; s > 0; s >>= 1) {
            if (tid < s) {
                float od = rd[tid + s]; int oi = ri_[tid + s];
                if (od < rd[tid] || (od == rd[tid] && oi < ri_[tid])) { rd[tid] = od; ri_[tid] = oi; }
            }
            __syncthreads();
        }
        if (tid == 0) bidx[row] = ri_[0];
    }
}

// ---------------- gather + loss + indices ----------------
__global__ void gather_kernel(const float* __restrict__ x, const float* __restrict__ cb,
                              const int* __restrict__ bidx, float* __restrict__ out,
                              float* __restrict__ loss_accum, int N) {
    __shared__ float wsum[4];
    const int tid = threadIdx.x;
    const int brow = blockIdx.x * BM;
    const size_t ND = (size_t)N * DDIM;
    if (tid < BM) out[ND + 1 + brow + tid] = (float)bidx[brow + tid];
    float lsum = 0.f;
    #pragma unroll 4
    for (int p = 0; p < 32; ++p) {
        int i = tid + p * 256;
        int row = i >> 6;
        int c4 = (i & 63) << 2;
        int code = bidx[brow + row];
        const float4 q = *reinterpret_cast<const float4*>(&cb[(size_t)code * DDIM + c4]);
        const float4 xv = *reinterpret_cast<const float4*>(&x[(size_t)(brow + row) * DDIM + c4]);
        float d0 = xv.x - q.x, d1 = xv.y - q.y, d2 = xv.z - q.z, d3 = xv.w - q.w;
        lsum += d0 * d0 + d1 * d1 + d2 * d2 + d3 * d3;
        *reinterpret_cast<float4*>(&out[(size_t)(brow + row) * DDIM + c4]) = q;
    }
    #pragma unroll
    for (int off = 32; off > 0; off >>= 1) lsum += __shfl_xor(lsum, off, 64);
    if ((tid & 63) == 0) wsum[tid >> 6] = lsum;
    __syncthreads();
    if (tid == 0) {
        float tot = wsum[0] + wsum[1] + wsum[2] + wsum[3];
        atomicAdd(loss_accum, tot * (0.25f / (float)ND));
    }
}

__global__ void loss_fin_kernel(const float* __restrict__ loss_accum,
                                float* __restrict__ out, size_t off) {
    if (blockIdx.x == 0 && threadIdx.x == 0) out[off] = *loss_accum;
}

extern "C" void kernel_launch(void* const* d_in, const int* in_sizes, int n_in,
                              void* d_out, int out_size, void* d_ws, size_t ws_size,
                              hipStream_t stream) {
    const float* x = (const float*)d_in[0];
    const float* cb = (const float*)d_in[1];
    const int N = in_sizes[0] / DDIM;    // 65536
    const int K = in_sizes[1] / DDIM;    // 4096
    float* out = (float*)d_out;

    // workspace layout
    half8* cb16 = (half8*)d_ws;                                        // 4 MB
    char* p = (char*)d_ws + (4 << 20);
    float* en = (float*)p;                 p += (size_t)K * 4;         // 16 KB
    int* bidx = (int*)p;                   p += (size_t)N * 4;         // 256 KB
    unsigned int* flags = (unsigned int*)p; p += (size_t)N * 4;        // 256 KB
    float* loss_accum = (float*)p;

    hipMemsetAsync(loss_accum, 0, sizeof(float), stream);
    cvt_cb_kernel<<<(K * 64) / 256, 256, 0, stream>>>(cb, cb16);
    enorm_kernel<<<(K * 64) / 256, 256, 0, stream>>>(cb, en, K);
    vq_mfma_kernel<<<N / BM, 512, 0, stream>>>(x, cb16, en, bidx, flags);
    rescan_kernel<<<N / 8, 256, 0, stream>>>(x, cb, en, flags, bidx);
    gather_kernel<<<N / BM, 256, 0, stream>>>(x, cb, bidx, out, loss_accum, N);
    loss_fin_kernel<<<1, 64, 0, stream>>>(loss_accum, out, (size_t)N * DDIM);
}

// Round 4
// 780.964 us; speedup vs baseline: 26.5043x; 26.5043x over previous
//
#include <hip/hip_runtime.h>
#include <hip/hip_bf16.h>
#include <stdint.h>

typedef _Float16 half8 __attribute__((ext_vector_type(8)));
typedef float f32x4 __attribute__((ext_vector_type(4)));

#define DDIM 256
#define KCODES 4096
#define BM 128
#define BN 256
#define NTILES (KCODES / BN)   // 16
#define NCHUNK (DDIM / 64)     // 4
#define DELTA 0.02f
#define FLT_BIG 3.4e38f

// ---------------- codebook -> fp16 hi/lo, layout [code][chunk][16B slot] ----------------
// slots per 64-dim chunk: 0-3 hi(d0..31), 4-7 lo(d0..31), 8-11 hi(d32..63), 12-15 lo(d32..63)
__global__ void cvt_cb_kernel(const float* __restrict__ cb, half8* __restrict__ cb16) {
    int gid = blockIdx.x * 256 + threadIdx.x;   // 4096*4*16 = 262144
    int slot = gid & 15;
    int chunk = (gid >> 4) & 3;
    int code = gid >> 6;
    int g = slot >> 3, part = (slot >> 2) & 1, quad = slot & 3;
    int d0 = chunk * 64 + g * 32 + quad * 8;
    const float* src = &cb[(size_t)code * DDIM + d0];
    half8 h;
    #pragma unroll
    for (int j = 0; j < 8; ++j) {
        float v = src[j];
        _Float16 hi = (_Float16)v;
        h[j] = part ? (_Float16)(v - (float)hi) : hi;
    }
    cb16[gid] = h;
}

__global__ void enorm_kernel(const float* __restrict__ cb, float* __restrict__ en, int K) {
    int gid = blockIdx.x * blockDim.x + threadIdx.x;
    int code = gid >> 6;
    int lane = threadIdx.x & 63;
    if (code >= K) return;
    const float4 v = *reinterpret_cast<const float4*>(&cb[(size_t)code * DDIM + lane * 4]);
    float s = v.x * v.x + v.y * v.y + v.z * v.z + v.w * v.w;
    #pragma unroll
    for (int off = 32; off > 0; off >>= 1) s += __shfl_xor(s, off, 64);
    if (lane == 0) en[code] = s;
}

// ---------------- main: MFMA distance GEMM + fused argmin + exact gap flag ----------------
__global__ __launch_bounds__(512, 2)
void vq_mfma_kernel(const float* __restrict__ x, const half8* __restrict__ cb16,
                    const float* __restrict__ en, int* __restrict__ bidx_out,
                    int* __restrict__ list, int* __restrict__ counter) {
    __shared__ __align__(16) _Float16 Asl[BM * 128];   // 32 KB
    __shared__ __align__(16) _Float16 Bsl[BN * 128];   // 64 KB
    __shared__ float red_d[4][BM];
    __shared__ float red_d2[4][BM];
    __shared__ int   red_i[4][BM];

    const int tid = threadIdx.x;
    const int lane = tid & 63;
    const int w = tid >> 6;
    const int wr = w >> 2, wc = w & 3;       // 2 x 4 waves
    const int l15 = lane & 15, l4 = lane >> 4;
    const int brow = blockIdx.x * BM;

    float best[16], best2[16];
    int bid[16];
    #pragma unroll
    for (int i = 0; i < 16; ++i) { best[i] = FLT_BIG; best2[i] = FLT_BIG; bid[i] = 0; }

    const int arow = tid >> 2;
    const int aq = tid & 3;
    const float* axp = &x[(size_t)(brow + arow) * DDIM + aq * 16];
    half8* Ap = (half8*)Asl;
    half8* Bp = (half8*)Bsl;
    const int aswz = arow & 7;
    const int abase = arow * 16;
    const int ah0 = (aq >> 1) * 8 + (aq & 1) * 2;

    for (int ct = 0; ct < NTILES; ++ct) {
        const int c0 = ct * BN;
        f32x4 acc[4][4];
        #pragma unroll
        for (int m = 0; m < 4; ++m)
            #pragma unroll
            for (int n = 0; n < 4; ++n) acc[m][n] = (f32x4){0.f, 0.f, 0.f, 0.f};

        for (int c = 0; c < NCHUNK; ++c) {
            __syncthreads();
            // ---- stage A (fp32 -> hi/lo fp16, swizzled ds_write) ----
            {
                const float4* ax4 = (const float4*)(axp + c * 64);
                float4 f0 = ax4[0], f1 = ax4[1], f2 = ax4[2], f3 = ax4[3];
                float vv[16] = {f0.x, f0.y, f0.z, f0.w, f1.x, f1.y, f1.z, f1.w,
                                f2.x, f2.y, f2.z, f2.w, f3.x, f3.y, f3.z, f3.w};
                half8 hv0, hv1, lv0, lv1;
                #pragma unroll
                for (int j = 0; j < 8; ++j) {
                    _Float16 h = (_Float16)vv[j];
                    hv0[j] = h; lv0[j] = (_Float16)(vv[j] - (float)h);
                }
                #pragma unroll
                for (int j = 0; j < 8; ++j) {
                    _Float16 h = (_Float16)vv[8 + j];
                    hv1[j] = h; lv1[j] = (_Float16)(vv[8 + j] - (float)h);
                }
                Ap[abase + ((ah0    ) ^ aswz)] = hv0;
                Ap[abase + ((ah0 + 1) ^ aswz)] = hv1;
                Ap[abase + ((ah0 + 4) ^ aswz)] = lv0;
                Ap[abase + ((ah0 + 5) ^ aswz)] = lv1;
            }
            // ---- stage B (pre-converted fp16, swizzled ds_write) ----
            #pragma unroll
            for (int i = 0; i < 8; ++i) {
                int S = i * 512 + tid;
                int r = S >> 4, l = S & 15;
                half8 v = cb16[((size_t)(c0 + r) * NCHUNK + c) * 16 + l];
                Bp[r * 16 + (l ^ (r & 7))] = v;
            }
            __syncthreads();

            // ---- MFMA: 2 k-groups x 3 split terms x 16 fragment-pairs ----
            #pragma unroll
            for (int g = 0; g < 2; ++g) {
                half8 ah[4], al[4], bh[4], bl[4];
                #pragma unroll
                for (int m = 0; m < 4; ++m) {
                    int row = wr * 64 + m * 16 + l15;
                    int sw = row & 7;
                    int sh = g * 8 + l4;
                    ah[m] = Ap[row * 16 + ((sh    ) ^ sw)];
                    al[m] = Ap[row * 16 + ((sh + 4) ^ sw)];
                }
                #pragma unroll
                for (int n = 0; n < 4; ++n) {
                    int col = wc * 64 + n * 16 + l15;
                    int sw = col & 7;
                    int sh = g * 8 + l4;
                    bh[n] = Bp[col * 16 + ((sh    ) ^ sw)];
                    bl[n] = Bp[col * 16 + ((sh + 4) ^ sw)];
                }
                #pragma unroll
                for (int m = 0; m < 4; ++m)
                    #pragma unroll
                    for (int n = 0; n < 4; ++n) {
                        acc[m][n] = __builtin_amdgcn_mfma_f32_16x16x32_f16(ah[m], bh[n], acc[m][n], 0, 0, 0);
                        acc[m][n] = __builtin_amdgcn_mfma_f32_16x16x32_f16(al[m], bh[n], acc[m][n], 0, 0, 0);
                        acc[m][n] = __builtin_amdgcn_mfma_f32_16x16x32_f16(ah[m], bl[n], acc[m][n], 0, 0, 0);
                    }
            }
        }

        // ---- fused argmin epilogue: dist = ||e||^2 - 2*dot ----
        #pragma unroll
        for (int n = 0; n < 4; ++n) {
            int code = c0 + wc * 64 + n * 16 + l15;
            float e = en[code];
            #pragma unroll
            for (int m = 0; m < 4; ++m) {
                #pragma unroll
                for (int r = 0; r < 4; ++r) {
                    float dist = fmaf(-2.f, acc[m][n][r], e);
                    int ri = m * 4 + r;
                    if (dist < best[ri]) {
                        best2[ri] = best[ri]; best[ri] = dist; bid[ri] = code;
                    } else if (dist < best2[ri]) {
                        best2[ri] = dist;
                    }
                }
            }
        }
    }

    // ---- cross-lane merge (16 lanes sharing the same rows; xor within lane bits 0-3) ----
    #pragma unroll
    for (int ri = 0; ri < 16; ++ri) {
        float d = best[ri], d2 = best2[ri];
        int ix = bid[ri];
        #pragma unroll
        for (int off = 1; off < 16; off <<= 1) {
            float od = __shfl_xor(d, off, 64);
            float od2 = __shfl_xor(d2, off, 64);
            int oi = __shfl_xor(ix, off, 64);
            if (od < d || (od == d && oi < ix)) {
                d2 = fminf(d, od2); d = od; ix = oi;
            } else {
                d2 = fminf(d2, od);
            }
        }
        if (l15 == 0) {
            int row = wr * 64 + (ri >> 2) * 16 + l4 * 4 + (ri & 3);
            red_d[wc][row] = d;
            red_d2[wc][row] = d2;
            red_i[wc][row] = ix;
        }
    }
    __syncthreads();

    // ---- cross-wave merge + write + flag append ----
    if (tid < BM) {
        float d = red_d[0][tid], d2 = red_d2[0][tid];
        int ix = red_i[0][tid];
        #pragma unroll
        for (int q = 1; q < 4; ++q) {
            float od = red_d[q][tid], od2 = red_d2[q][tid];
            int oi = red_i[q][tid];
            if (od < d || (od == d && oi < ix)) {
                d2 = fminf(d, od2); d = od; ix = oi;
            } else {
                d2 = fminf(d2, od);
            }
        }
        bidx_out[brow + tid] = ix;
        if (d2 - d < DELTA) {
            int pos = atomicAdd(counter, 1);
            list[pos] = brow + tid;
        }
    }
}

// ---------------- exact fp32 rescan: compacted list, wave-per-code coalesced ----------------
__global__ __launch_bounds__(256)
void rescan_kernel(const float* __restrict__ x, const float* __restrict__ cb,
                   const float* __restrict__ en, const int* __restrict__ list,
                   const int* __restrict__ counter, int* __restrict__ bidx) {
    __shared__ __align__(16) float4 xrow4[64];
    __shared__ float wd[4];
    __shared__ int wi[4];
    const int tid = threadIdx.x;
    const int w = tid >> 6;
    const int lane = tid & 63;
    const int cnt = *counter;

    for (int it = blockIdx.x; it < cnt; it += gridDim.x) {
        const int row = list[it];
        __syncthreads();
        if (tid < 64) xrow4[tid] = ((const float4*)&x[(size_t)row * DDIM])[tid];
        __syncthreads();
        const float4 xv = xrow4[lane];
        float bd = FLT_BIG;
        int bi = 0;
        for (int i = 0; i < KCODES / 4; ++i) {
            int code = i * 4 + w;
            const float4 c4 = ((const float4*)&cb[(size_t)code * DDIM])[lane];
            float s = xv.x * c4.x + xv.y * c4.y + xv.z * c4.z + xv.w * c4.w;
            #pragma unroll
            for (int off = 1; off < 64; off <<= 1) s += __shfl_xor(s, off, 64);
            float dist = fmaf(-2.f, s, en[code]);
            if (dist < bd) { bd = dist; bi = code; }   // ascending code order per wave
        }
        if (lane == 0) { wd[w] = bd; wi[w] = bi; }
        __syncthreads();
        if (tid == 0) {
            float d = wd[0]; int ix = wi[0];
            #pragma unroll
            for (int q = 1; q < 4; ++q) {
                if (wd[q] < d || (wd[q] == d && wi[q] < ix)) { d = wd[q]; ix = wi[q]; }
            }
            bidx[row] = ix;
        }
    }
}

// ---------------- gather + loss + indices ----------------
__global__ void gather_kernel(const float* __restrict__ x, const float* __restrict__ cb,
                              const int* __restrict__ bidx, float* __restrict__ out,
                              float* __restrict__ loss_accum, int N) {
    __shared__ float wsum[4];
    const int tid = threadIdx.x;
    const int brow = blockIdx.x * BM;
    const size_t ND = (size_t)N * DDIM;
    if (tid < BM) out[ND + 1 + brow + tid] = (float)bidx[brow + tid];
    float lsum = 0.f;
    #pragma unroll 4
    for (int p = 0; p < 32; ++p) {
        int i = tid + p * 256;
        int row = i >> 6;
        int c4 = (i & 63) << 2;
        int code = bidx[brow + row];
        const float4 q = *reinterpret_cast<const float4*>(&cb[(size_t)code * DDIM + c4]);
        const float4 xv = *reinterpret_cast<const float4*>(&x[(size_t)(brow + row) * DDIM + c4]);
        float d0 = xv.x - q.x, d1 = xv.y - q.y, d2 = xv.z - q.z, d3 = xv.w - q.w;
        lsum += d0 * d0 + d1 * d1 + d2 * d2 + d3 * d3;
        *reinterpret_cast<float4*>(&out[(size_t)(brow + row) * DDIM + c4]) = q;
    }
    #pragma unroll
    for (int off = 32; off > 0; off >>= 1) lsum += __shfl_xor(lsum, off, 64);
    if ((tid & 63) == 0) wsum[tid >> 6] = lsum;
    __syncthreads();
    if (tid == 0) {
        float tot = wsum[0] + wsum[1] + wsum[2] + wsum[3];
        atomicAdd(loss_accum, tot * (0.25f / (float)ND));
    }
}

__global__ void loss_fin_kernel(const float* __restrict__ loss_accum,
                                float* __restrict__ out, size_t off) {
    if (blockIdx.x == 0 && threadIdx.x == 0) out[off] = *loss_accum;
}

extern "C" void kernel_launch(void* const* d_in, const int* in_sizes, int n_in,
                              void* d_out, int out_size, void* d_ws, size_t ws_size,
                              hipStream_t stream) {
    const float* x = (const float*)d_in[0];
    const float* cb = (const float*)d_in[1];
    const int N = in_sizes[0] / DDIM;    // 65536
    const int K = in_sizes[1] / DDIM;    // 4096
    float* out = (float*)d_out;

    // workspace layout
    half8* cb16 = (half8*)d_ws;                                         // 4 MB
    char* p = (char*)d_ws + (4 << 20);
    float* en = (float*)p;                  p += (size_t)K * 4;
    int* bidx = (int*)p;                    p += (size_t)N * 4;
    int* list = (int*)p;                    p += (size_t)N * 4;
    int* counter = (int*)p;                 p += 64;
    float* loss_accum = (float*)p;

    hipMemsetAsync(counter, 0, sizeof(int), stream);
    hipMemsetAsync(loss_accum, 0, sizeof(float), stream);
    cvt_cb_kernel<<<(K * 64) / 256, 256, 0, stream>>>(cb, cb16);
    enorm_kernel<<<(K * 64) / 256, 256, 0, stream>>>(cb, en, K);
    vq_mfma_kernel<<<N / BM, 512, 0, stream>>>(x, cb16, en, bidx, list, counter);
    rescan_kernel<<<512, 256, 0, stream>>>(x, cb, en, list, counter, bidx);
    gather_kernel<<<N / BM, 256, 0, stream>>>(x, cb, bidx, out, loss_accum, N);
    loss_fin_kernel<<<1, 64, 0, stream>>>(loss_accum, out, (size_t)N * DDIM);
}